// Round 3
// baseline (428.946 us; speedup 1.0000x reference)
//
#include <hip/hip_runtime.h>
#include <math.h>

#define NN 50000
#define NE 800000
#define D  128
#define SCAN_CHUNK 1024
#define NSCAN ((NN + SCAN_CHUNK - 1) / SCAN_CHUNK)   // 49

// ---------------- in-degree histogram (dst), int4-vectorized ----------------
__global__ __launch_bounds__(320) void k_deg(const int* __restrict__ ei,
                                             int* __restrict__ deg) {
    int t = blockIdx.x * 320 + threadIdx.x;       // 625 blocks * 320 * 4 = NE
    int4 d4 = ((const int4*)(ei + NE))[t];
    atomicAdd(&deg[d4.x], 1);
    atomicAdd(&deg[d4.y], 1);
    atomicAdd(&deg[d4.z], 1);
    atomicAdd(&deg[d4.w], 1);
}

// ---------------- scan stage A: per-chunk sums + dinv ----------------
__global__ __launch_bounds__(256) void k_scan_a(const int* __restrict__ deg,
                                                int* __restrict__ partial,
                                                float* __restrict__ dinv) {
    __shared__ int red[256];
    int t = threadIdx.x;
    int base = blockIdx.x * SCAN_CHUNK + t * 4;
    int s = 0;
#pragma unroll
    for (int j = 0; j < 4; j++) {
        int i = base + j;
        if (i < NN) {
            int d = deg[i];
            s += d;
            dinv[i] = rsqrtf((float)d + 1.0f);   // +1 self loop
        }
    }
    red[t] = s; __syncthreads();
#pragma unroll
    for (int off = 128; off > 0; off >>= 1) {
        if (t < off) red[t] += red[t + off];
        __syncthreads();
    }
    if (t == 0) partial[blockIdx.x] = red[0];
}

// ---------------- scan stage C: block prefix via shuffle + chunk scan --------
__global__ __launch_bounds__(256) void k_scan_c(const int* __restrict__ deg,
                                                const int* __restrict__ partial,
                                                int* __restrict__ rowoff,
                                                int* __restrict__ cur) {
    __shared__ int sbuf[256];
    int t = threadIdx.x;
    int lane = t & 63;
    // sum of partial[0..blockIdx) computed redundantly per wave
    int pv = (lane < NSCAN && lane < (int)blockIdx.x) ? partial[lane] : 0;
#pragma unroll
    for (int off = 32; off > 0; off >>= 1) pv += __shfl_xor(pv, off, 64);

    int base = blockIdx.x * SCAN_CHUNK + t * 4;
    int d[4]; int s = 0;
#pragma unroll
    for (int j = 0; j < 4; j++) {
        d[j] = (base + j < NN) ? deg[base + j] : 0;
        s += d[j];
    }
    sbuf[t] = s; __syncthreads();
    for (int off = 1; off < 256; off <<= 1) {
        int v = (t >= off) ? sbuf[t - off] : 0;
        __syncthreads();
        sbuf[t] += v;
        __syncthreads();
    }
    int ex = sbuf[t] - s + pv;
#pragma unroll
    for (int j = 0; j < 4; j++) {
        int i = base + j;
        if (i < NN) {
            rowoff[i] = ex; cur[i] = ex;
            ex += d[j];
            if (i == NN - 1) rowoff[NN] = ex;   // sentinel = NE
        }
    }
}

// ---------------- CSR fill (counting-sort placement), int4 ----------------
__global__ __launch_bounds__(320) void k_fill(const int* __restrict__ ei,
                                              int* __restrict__ cur,
                                              int* __restrict__ csr) {
    int t = blockIdx.x * 320 + threadIdx.x;
    int4 s4 = ((const int4*)ei)[t];
    int4 d4 = ((const int4*)(ei + NE))[t];
    csr[atomicAdd(&cur[d4.x], 1)] = s4.x;
    csr[atomicAdd(&cur[d4.y], 1)] = s4.y;
    csr[atomicAdd(&cur[d4.z], 1)] = s4.z;
    csr[atomicAdd(&cur[d4.w], 1)] = s4.w;
}

// ---------------- fused: gather + GEMM + bias + LN + tanh ----------------
// Block 256 = 4 waves, 32 rows/block, wave w owns rows rowBase+8w..+7.
// Lane owns adjacent cols (2*lane, 2*lane+1).
__global__ __launch_bounds__(256) void k_main(
        const int* __restrict__ rowoff, const int* __restrict__ csr,
        const float* __restrict__ dinv, const float* __restrict__ h,
        const float* __restrict__ Wg,   const float* __restrict__ bias,
        const float* __restrict__ gamma,const float* __restrict__ beta,
        float* __restrict__ out) {
    __shared__ float Wl[D * D];    // 64 KB, flat copy of W (row-major [k][col])
    __shared__ float xs[32][D];    // 16 KB
    int tid = threadIdx.x;

    // stage W cooperatively (float4-coalesced, L2-warm after first blocks)
#pragma unroll
    for (int i = 0; i < 16; i++)
        ((float4*)Wl)[i * 256 + tid] = ((const float4*)Wg)[i * 256 + tid];

    int w = tid >> 6, lane = tid & 63;
    int rowBase = blockIdx.x * 32 + w * 8;
    const float2* h2 = (const float2*)h;

    // ---- gather phase: x[row] = dn*(dn*h[row] + sum dinv[s]*h[s]) ----
    for (int r = 0; r < 8; r++) {
        int row = rowBase + r;
        float2 x = make_float2(0.f, 0.f);
        if (row < NN) {
            float dn = dinv[row];
            int start = rowoff[row];
            int nE = rowoff[row + 1] - start;
            float2 hv = h2[(size_t)row * 64 + lane];
            x.x = dn * hv.x; x.y = dn * hv.y;
            for (int c = 0; c < nE; c += 64) {
                int rem = nE - c;
                int m = rem < 64 ? rem : 64;
                int s = 0; float wv = 0.f;
                if (lane < m) { s = csr[start + c + lane]; wv = dinv[s]; }
                for (int j = 0; j < m; j++) {
                    int   sj = __shfl(s,  j, 64);
                    float wj = __shfl(wv, j, 64);
                    float2 hj = h2[(size_t)sj * 64 + lane];
                    x.x = fmaf(wj, hj.x, x.x);
                    x.y = fmaf(wj, hj.y, x.y);
                }
            }
            x.x *= dn; x.y *= dn;
        }
        *(float2*)&xs[w * 8 + r][lane * 2] = x;
    }
    __syncthreads();   // covers W staging + all xs writes

    // ---- GEMM phase ----
    const float2* W2 = (const float2*)Wl;    // [k][64] float2 pairs
    float2 bi = ((const float2*)bias)[lane];
    float2 ga = ((const float2*)gamma)[lane];
    float2 be = ((const float2*)beta)[lane];

    int rbase = w * 8;
    float2 acc[8];
#pragma unroll
    for (int r = 0; r < 8; r++) acc[r] = make_float2(0.f, 0.f);

    for (int k4 = 0; k4 < D; k4 += 4) {
        float4 xv[8];
#pragma unroll
        for (int r = 0; r < 8; r++) xv[r] = *(const float4*)&xs[rbase + r][k4];
#pragma unroll
        for (int kk = 0; kk < 4; kk++) {
            float2 wv = W2[(k4 + kk) * 64 + lane];   // ds_read_b64
#pragma unroll
            for (int r = 0; r < 8; r++) {
                float xk = ((const float*)&xv[r])[kk];
                acc[r].x = fmaf(xk, wv.x, acc[r].x);
                acc[r].y = fmaf(xk, wv.y, acc[r].y);
            }
        }
    }

    // ---- bias + LN + tanh + store ----
#pragma unroll
    for (int r = 0; r < 8; r++) {
        int row = rowBase + r;
        float y0 = acc[r].x + bi.x;
        float y1 = acc[r].y + bi.y;
        float s = y0 + y1;
#pragma unroll
        for (int off = 32; off > 0; off >>= 1) s += __shfl_xor(s, off, 64);
        float m = s * (1.0f / 128.0f);
        float v0 = y0 - m, v1 = y1 - m;
        float vs = v0 * v0 + v1 * v1;
#pragma unroll
        for (int off = 32; off > 0; off >>= 1) vs += __shfl_xor(vs, off, 64);
        float rstd = rsqrtf(vs * (1.0f / 128.0f) + 1e-5f);
        if (row < NN) {
            float2 o;
            o.x = tanhf(v0 * rstd * ga.x + be.x);
            o.y = tanhf(v1 * rstd * ga.y + be.y);
            *(float2*)&out[(size_t)row * D + lane * 2] = o;
        }
    }
}

extern "C" void kernel_launch(void* const* d_in, const int* in_sizes, int n_in,
                              void* d_out, int out_size, void* d_ws, size_t ws_size,
                              hipStream_t stream) {
    // inputs: t, h, edge_index, batch_size, W, b, gamma, beta
    const float* h     = (const float*)d_in[1];
    const int*   ei    = (const int*)  d_in[2];
    const float* Wg    = (const float*)d_in[4];
    const float* b     = (const float*)d_in[5];
    const float* gamma = (const float*)d_in[6];
    const float* beta  = (const float*)d_in[7];
    float* out = (float*)d_out;

    // workspace layout
    int*   deg    = (int*)d_ws;                 // NN
    int*   cur    = deg + NN;                   // NN
    int*   rowoff = cur + NN;                   // NN + 1
    float* dinv   = (float*)(rowoff + NN + 1);  // NN
    int*   partial= (int*)(dinv + NN);          // 64
    int*   csr    = partial + 64;               // NE

    hipMemsetAsync(deg, 0, NN * sizeof(int), stream);
    // zero tail outputs (zeros_like(edge_index) + zeros_like(batch_size))
    size_t dh_bytes  = (size_t)NN * D * sizeof(float);
    size_t out_bytes = (size_t)out_size * sizeof(float);
    if (out_bytes > dh_bytes)
        hipMemsetAsync((char*)d_out + dh_bytes, 0, out_bytes - dh_bytes, stream);

    k_deg   <<<625,   320, 0, stream>>>(ei, deg);
    k_scan_a<<<NSCAN, 256, 0, stream>>>(deg, partial, dinv);
    k_scan_c<<<NSCAN, 256, 0, stream>>>(deg, partial, rowoff, cur);
    k_fill  <<<625,   320, 0, stream>>>(ei, cur, csr);
    k_main  <<<(NN + 31) / 32, 256, 0, stream>>>(rowoff, csr, dinv, h, Wg, b, gamma, beta, out);
}

// Round 4
// 351.037 us; speedup vs baseline: 1.2219x; 1.2219x over previous
//
#include <hip/hip_runtime.h>
#include <math.h>

#define NN 50000
#define NE 800000
#define D  128
#define SCAN_CHUNK 1024
#define NSCAN ((NN + SCAN_CHUNK - 1) / SCAN_CHUNK)   // 49

// ---------------- in-degree histogram (dst), int4-vectorized ----------------
__global__ __launch_bounds__(320) void k_deg(const int* __restrict__ ei,
                                             int* __restrict__ deg) {
    int t = blockIdx.x * 320 + threadIdx.x;       // 625 blocks * 320 * 4 = NE
    int4 d4 = ((const int4*)(ei + NE))[t];
    atomicAdd(&deg[d4.x], 1);
    atomicAdd(&deg[d4.y], 1);
    atomicAdd(&deg[d4.z], 1);
    atomicAdd(&deg[d4.w], 1);
}

// ---------------- scan stage A: per-chunk sums + dinv ----------------
__global__ __launch_bounds__(256) void k_scan_a(const int* __restrict__ deg,
                                                int* __restrict__ partial,
                                                float* __restrict__ dinv) {
    __shared__ int red[256];
    int t = threadIdx.x;
    int base = blockIdx.x * SCAN_CHUNK + t * 4;
    int s = 0;
#pragma unroll
    for (int j = 0; j < 4; j++) {
        int i = base + j;
        if (i < NN) {
            int d = deg[i];
            s += d;
            dinv[i] = rsqrtf((float)d + 1.0f);   // +1 self loop
        }
    }
    red[t] = s; __syncthreads();
#pragma unroll
    for (int off = 128; off > 0; off >>= 1) {
        if (t < off) red[t] += red[t + off];
        __syncthreads();
    }
    if (t == 0) partial[blockIdx.x] = red[0];
}

// ---------------- scan stage C: block prefix via shuffle + chunk scan --------
__global__ __launch_bounds__(256) void k_scan_c(const int* __restrict__ deg,
                                                const int* __restrict__ partial,
                                                int* __restrict__ rowoff,
                                                int* __restrict__ cur) {
    __shared__ int sbuf[256];
    int t = threadIdx.x;
    int lane = t & 63;
    int pv = (lane < NSCAN && lane < (int)blockIdx.x) ? partial[lane] : 0;
#pragma unroll
    for (int off = 32; off > 0; off >>= 1) pv += __shfl_xor(pv, off, 64);

    int base = blockIdx.x * SCAN_CHUNK + t * 4;
    int d[4]; int s = 0;
#pragma unroll
    for (int j = 0; j < 4; j++) {
        d[j] = (base + j < NN) ? deg[base + j] : 0;
        s += d[j];
    }
    sbuf[t] = s; __syncthreads();
    for (int off = 1; off < 256; off <<= 1) {
        int v = (t >= off) ? sbuf[t - off] : 0;
        __syncthreads();
        sbuf[t] += v;
        __syncthreads();
    }
    int ex = sbuf[t] - s + pv;
#pragma unroll
    for (int j = 0; j < 4; j++) {
        int i = base + j;
        if (i < NN) {
            rowoff[i] = ex; cur[i] = ex;
            ex += d[j];
            if (i == NN - 1) rowoff[NN] = ex;   // sentinel = NE
        }
    }
}

// ---------------- CSR fill (counting-sort placement), int4 ----------------
__global__ __launch_bounds__(320) void k_fill(const int* __restrict__ ei,
                                              int* __restrict__ cur,
                                              int* __restrict__ csr) {
    int t = blockIdx.x * 320 + threadIdx.x;
    int4 s4 = ((const int4*)ei)[t];
    int4 d4 = ((const int4*)(ei + NE))[t];
    csr[atomicAdd(&cur[d4.x], 1)] = s4.x;
    csr[atomicAdd(&cur[d4.y], 1)] = s4.y;
    csr[atomicAdd(&cur[d4.z], 1)] = s4.z;
    csr[atomicAdd(&cur[d4.w], 1)] = s4.w;
}

// ---------------- fused: gather + GEMM + bias + LN + tanh (NO LDS) ----------
// Block 256 = 4 independent waves; each wave owns 8 rows. Lane owns output
// cols (2*lane, 2*lane+1) and holds x dims (2*lane, 2*lane+1) in registers.
__global__ __launch_bounds__(256) void k_main(
        const int* __restrict__ rowoff, const int* __restrict__ csr,
        const float* __restrict__ dinv, const float* __restrict__ h,
        const float* __restrict__ Wg,   const float* __restrict__ bias,
        const float* __restrict__ gamma,const float* __restrict__ beta,
        float* __restrict__ out) {
    int tid = threadIdx.x;
    int w = tid >> 6, lane = tid & 63;
    int rowBase = blockIdx.x * 32 + w * 8;
    const float2* h2 = (const float2*)h;
    const float2* W2 = (const float2*)Wg;

    // ---- gather into registers: x[r] = dn*(dn*h[row] + sum dinv[s]*h[s]) ----
    float2 x[8];
    for (int r = 0; r < 8; r++) {
        int row = rowBase + r;
        float2 a = make_float2(0.f, 0.f);
        if (row < NN) {
            float dn = dinv[row];
            float2 hv = h2[(size_t)row * 64 + lane];
            a.x = dn * hv.x; a.y = dn * hv.y;
            int start = rowoff[row], end = rowoff[row + 1];
            for (int c = start; c < end; c += 64) {
                int m = end - c; if (m > 64) m = 64;
                int s = 0; float wv = 0.f;
                if (lane < m) { s = csr[c + lane]; wv = dinv[s]; }
                for (int j = 0; j < m; j++) {
                    int   sj = __shfl(s,  j, 64);
                    float wj = __shfl(wv, j, 64);
                    float2 hj = h2[(size_t)sj * 64 + lane];
                    a.x = fmaf(wj, hj.x, a.x);
                    a.y = fmaf(wj, hj.y, a.y);
                }
            }
            a.x *= dn; a.y *= dn;
        }
        x[r] = a;
    }

    // ---- GEMM via register broadcast: y[c] = sum_k x[k] * W[k][c] ----
    float2 acc[8];
#pragma unroll
    for (int r = 0; r < 8; r++) acc[r] = make_float2(0.f, 0.f);

    // even k = 2j: x[2j] lives in lane j's .x
#pragma unroll 4
    for (int j = 0; j < 64; j++) {
        float2 wv = W2[(size_t)(2 * j) * 64 + lane];
#pragma unroll
        for (int r = 0; r < 8; r++) {
            float xk = __shfl(x[r].x, j, 64);
            acc[r].x = fmaf(xk, wv.x, acc[r].x);
            acc[r].y = fmaf(xk, wv.y, acc[r].y);
        }
    }
    // odd k = 2j+1: x[2j+1] lives in lane j's .y
#pragma unroll 4
    for (int j = 0; j < 64; j++) {
        float2 wv = W2[(size_t)(2 * j + 1) * 64 + lane];
#pragma unroll
        for (int r = 0; r < 8; r++) {
            float xk = __shfl(x[r].y, j, 64);
            acc[r].x = fmaf(xk, wv.x, acc[r].x);
            acc[r].y = fmaf(xk, wv.y, acc[r].y);
        }
    }

    // ---- bias + LN + tanh + store ----
    float2 bi = ((const float2*)bias)[lane];
    float2 ga = ((const float2*)gamma)[lane];
    float2 be = ((const float2*)beta)[lane];
#pragma unroll
    for (int r = 0; r < 8; r++) {
        int row = rowBase + r;
        float y0 = acc[r].x + bi.x;
        float y1 = acc[r].y + bi.y;
        float s = y0 + y1;
#pragma unroll
        for (int off = 32; off > 0; off >>= 1) s += __shfl_xor(s, off, 64);
        float m = s * (1.0f / 128.0f);
        float v0 = y0 - m, v1 = y1 - m;
        float vs = v0 * v0 + v1 * v1;
#pragma unroll
        for (int off = 32; off > 0; off >>= 1) vs += __shfl_xor(vs, off, 64);
        float rstd = rsqrtf(vs * (1.0f / 128.0f) + 1e-5f);
        if (row < NN) {
            float2 o;
            o.x = tanhf(v0 * rstd * ga.x + be.x);
            o.y = tanhf(v1 * rstd * ga.y + be.y);
            *(float2*)&out[(size_t)row * D + lane * 2] = o;
        }
    }
}

extern "C" void kernel_launch(void* const* d_in, const int* in_sizes, int n_in,
                              void* d_out, int out_size, void* d_ws, size_t ws_size,
                              hipStream_t stream) {
    // inputs: t, h, edge_index, batch_size, W, b, gamma, beta
    const float* h     = (const float*)d_in[1];
    const int*   ei    = (const int*)  d_in[2];
    const float* Wg    = (const float*)d_in[4];
    const float* b     = (const float*)d_in[5];
    const float* gamma = (const float*)d_in[6];
    const float* beta  = (const float*)d_in[7];
    float* out = (float*)d_out;

    // workspace layout
    int*   deg    = (int*)d_ws;                 // NN
    int*   cur    = deg + NN;                   // NN
    int*   rowoff = cur + NN;                   // NN + 1
    float* dinv   = (float*)(rowoff + NN + 1);  // NN
    int*   partial= (int*)(dinv + NN);          // 64
    int*   csr    = partial + 64;               // NE

    hipMemsetAsync(deg, 0, NN * sizeof(int), stream);
    // zero tail outputs (zeros_like(edge_index) + zeros_like(batch_size))
    size_t dh_bytes  = (size_t)NN * D * sizeof(float);
    size_t out_bytes = (size_t)out_size * sizeof(float);
    if (out_bytes > dh_bytes)
        hipMemsetAsync((char*)d_out + dh_bytes, 0, out_bytes - dh_bytes, stream);

    k_deg   <<<625,   320, 0, stream>>>(ei, deg);
    k_scan_a<<<NSCAN, 256, 0, stream>>>(deg, partial, dinv);
    k_scan_c<<<NSCAN, 256, 0, stream>>>(deg, partial, rowoff, cur);
    k_fill  <<<625,   320, 0, stream>>>(ei, cur, csr);
    k_main  <<<(NN + 31) / 32, 256, 0, stream>>>(rowoff, csr, dinv, h, Wg, b, gamma, beta, out);
}